// Round 4
// baseline (723.328 us; speedup 1.0000x reference)
//
#include <hip/hip_runtime.h>
#include <cstdint>

typedef unsigned int u32;
typedef unsigned short u16;
typedef _Float16 h2 __attribute__((ext_vector_type(2)));

// ---------------- workspace byte offsets (written by vit_prep) ----------------
#define WS_W1A   0        // [3*16*49][8] f16 : W1 i<8   (Q rows pre-scaled 1/7)
#define WS_W1B   37632    // [3*16*49][8] f16 : W1 i 8..16
#define WS_CQ    75264    // f32[2352]  pos-emb-folded bias (Q part pre-scaled)
#define WS_W2A   84672    // [3*8*49][8] f16 : W2 i<8 (Q rows pre-scaled 1/7)
#define WS_W2B   103488   // [3*8*49][8] f16 : W2 i 8..16
#define WS_F1H   122304   // u32[16*196] fc1 weights as f16 pairs (bias NOT folded)
#define WS_F1B   134848   // f32[16]
#define WS_F2W   134912   // f32[160]
#define WS_F2B   135552   // f32[10]

__device__ __forceinline__ u32 packh2(float a, float b) {
  h2 h; h.x = (_Float16)a; h.y = (_Float16)b;
  return __builtin_bit_cast(u32, h);
}
__device__ __forceinline__ float dot2u(u32 a, u32 b, float c) {
#if __has_builtin(__builtin_amdgcn_fdot2)
  return __builtin_amdgcn_fdot2(__builtin_bit_cast(h2, a), __builtin_bit_cast(h2, b), c, false);
#else
  h2 ha = __builtin_bit_cast(h2, a), hb = __builtin_bit_cast(h2, b);
  return c + (float)ha.x * (float)hb.x + (float)ha.y * (float)hb.y;
#endif
}
__device__ __forceinline__ float dot16(const u32* t, uint4 a, uint4 b, float c) {
  c = dot2u(t[0], a.x, c); c = dot2u(t[1], a.y, c);
  c = dot2u(t[2], a.z, c); c = dot2u(t[3], a.w, c);
  c = dot2u(t[4], b.x, c); c = dot2u(t[5], b.y, c);
  c = dot2u(t[6], b.z, c); c = dot2u(t[7], b.w, c);
  return c;
}

// ---------------- prep (unchanged) ----------------
extern "C" __global__ void vit_prep(
    const float* __restrict__ pe,
    const float* __restrict__ wq1, const float* __restrict__ wk1, const float* __restrict__ wv1,
    const float* __restrict__ wq2, const float* __restrict__ wk2, const float* __restrict__ wv2,
    const float* __restrict__ fw1, const float* __restrict__ fb1,
    const float* __restrict__ fw2, const float* __restrict__ fb2,
    char* __restrict__ ws)
{
  const int t = blockIdx.x * 256 + threadIdx.x;
  _Float16* w1aH = (_Float16*)(ws + WS_W1A);
  _Float16* w1bH = (_Float16*)(ws + WS_W1B);
  float*    cq   = (float*)(ws + WS_CQ);
  _Float16* w2aH = (_Float16*)(ws + WS_W2A);
  _Float16* w2bH = (_Float16*)(ws + WS_W2B);
  u32* f1h = (u32*)(ws + WS_F1H);
  float* o1b = (float*)(ws + WS_F1B);
  float* o2w = (float*)(ws + WS_F2W);
  float* o2b = (float*)(ws + WS_F2B);

  if (t < 2352) {                       // W1 rows: t = (p*16+o)*49+s
    int p = t / 784, rem = t % 784;
    int o = rem / 49, s = rem % 49;
    const float* W = (p == 0 ? wq1 : (p == 1 ? wk1 : wv1)) + s*512 + o*32;
    float sc = (p == 0) ? (1.0f/7.0f) : 1.0f;   // fold attn scale into Q
    #pragma unroll
    for (int i = 0; i < 8; ++i) w1aH[t*8 + i] = (_Float16)(W[i] * sc);
    #pragma unroll
    for (int i = 0; i < 8; ++i) w1bH[t*8 + i] = (_Float16)(W[8 + i] * sc);
    float acc = 0.f;
    #pragma unroll
    for (int i = 0; i < 16; ++i) acc += pe[s*16 + i] * W[16 + i];
    cq[t] = acc * sc;
  } else if (t < 3528) {                // W2 rows: u = (p*8+o)*49+s
    int u = t - 2352;
    int p = u / 392, rem = u % 392;
    int o = rem / 49, s = rem % 49;
    const float* W = (p == 0 ? wq2 : (p == 1 ? wk2 : wv2)) + s*128 + o*16;
    float sc = (p == 0) ? (1.0f/7.0f) : 1.0f;
    #pragma unroll
    for (int i = 0; i < 8; ++i) w2aH[u*8 + i] = (_Float16)(W[i] * sc);
    #pragma unroll
    for (int i = 0; i < 8; ++i) w2bH[u*8 + i] = (_Float16)(W[8 + i] * sc);
  } else if (t < 6664) {                // fc1 f16 pairs: u = h*196 + jc
    int u = t - 3528;
    int h = u / 196, jc = u % 196;
    f1h[u] = packh2(fw1[h*392 + 2*jc], fw1[h*392 + 2*jc + 1]);
  } else if (t < 6680) {
    int u = t - 6664; o1b[u] = fb1[u];
  } else if (t < 6840) {
    int u = t - 6680; o2w[u] = fw2[u];
  } else if (t < 6850) {
    int u = t - 6840; o2b[u] = fb2[u];
  }
}

// ---------------- main fused kernel ----------------
// block=256 (4 waves), grid=256, 8 iters, NS=2 samples/wave/iter.
// ALL weights from global (L2-resident ~135 KB). LDS = per-wave scratch only:
//   per sample region 4096 B:
//     su+0    : Q1 f16 [16][56] (1792)  -> later Q2 [8][56] (896) / K2 @+896 / t3h u32[49][4] (784)
//     su+1792 : K1 f16 [16][56] (1792)
//     su+3584 : S1 u32[16][8] (512) -> S2 u32[8][4] @+0; prt f32[16][2] @+192; lg f32[10] @+384
// block LDS = 4 waves * 2 * 4096 = 32768 B -> 4 blocks/CU (16 waves/CU).
extern "C" __global__ void __launch_bounds__(256, 4)
vit_main(const float* __restrict__ x, const char* __restrict__ ws, float* __restrict__ out)
{
  __shared__ uint4 smem4[32768 / 16];
  char* smem = (char*)smem4;
  const u32 tid  = threadIdx.x;
  const u32 lane = tid & 63u;
  const u32 wv   = tid >> 6;

  const uint4* g1a = (const uint4*)(ws + WS_W1A);
  const uint4* g1b = (const uint4*)(ws + WS_W1B);
  const float* gcq = (const float*)(ws + WS_CQ);
  const uint4* g2a = (const uint4*)(ws + WS_W2A);
  const uint4* g2b = (const uint4*)(ws + WS_W2B);
  const uint4* f1hg = (const uint4*)(ws + WS_F1H);
  const float* f1bg = (const float*)(ws + WS_F1B);
  const float* f2wg = (const float*)(ws + WS_F2W);
  const float* f2bg = (const float*)(ws + WS_F2B);

  char* pw = smem + wv * 8192;
  const u32 s = lane;
  const u32 pr = s / 7u, pc = s - pr * 7u;

  for (u32 iter = 0; iter < 8u; ++iter) {
    const u32 bbase = blockIdx.x * 64u + iter * 8u + wv * 2u;

    u32 p2h[2][8];   // patch h2 pairs
    u32 v1h[2][8];   // V1 e-pairs
    u32 th4[2][8];   // tok2 pairs
    u32 v2h[2][4];   // V2 e-pairs

    // ---- P1: patchify to registers ----
    if (s < 49u) {
      #pragma unroll
      for (int u = 0; u < 2; ++u) {
        const float* xb = x + (size_t)(bbase + u) * 2352u;
        #pragma unroll
        for (int r = 0; r < 4; ++r) {
          const float* rp = xb + (4u*pr + r) * 28u + 4u*pc;
          float4 rr = *(const float4*)rp;
          float4 gg = *(const float4*)(rp + 784);
          float4 bb = *(const float4*)(rp + 1568);
          float g0 = 0.299f*rr.x + 0.587f*gg.x + 0.114f*bb.x;
          float g1 = 0.299f*rr.y + 0.587f*gg.y + 0.114f*bb.y;
          float g2 = 0.299f*rr.z + 0.587f*gg.z + 0.114f*bb.z;
          float g3 = 0.299f*rr.w + 0.587f*gg.w + 0.114f*bb.w;
          p2h[u][r*2]   = packh2(g0, g1);
          p2h[u][r*2+1] = packh2(g2, g3);
        }
      }
    }

    // ---- P2: proj1 from global weights (QKV-split to bound reg pressure) ----
    if (s < 49u) {
      #pragma unroll
      for (int op = 0; op < 8; ++op) {
        const int o = 2*op;
        const int r0 = o*49 + (int)s;
        { // Q
          uint4 a0 = g1a[r0], b0 = g1b[r0], a1 = g1a[r0+49], b1 = g1b[r0+49];
          float c0 = gcq[r0], c1 = gcq[r0+49];
          #pragma unroll
          for (int u = 0; u < 2; ++u) {
            _Float16* qrow = (_Float16*)(pw + u*4096);
            qrow[o*56 + s]     = (_Float16)dot16(p2h[u], a0, b0, c0);
            qrow[(o+1)*56 + s] = (_Float16)dot16(p2h[u], a1, b1, c1);
          }
        }
        { // K
          uint4 a0 = g1a[r0+784], b0 = g1b[r0+784], a1 = g1a[r0+833], b1 = g1b[r0+833];
          float c0 = gcq[r0+784], c1 = gcq[r0+833];
          #pragma unroll
          for (int u = 0; u < 2; ++u) {
            _Float16* krow = (_Float16*)(pw + u*4096 + 1792);
            krow[o*56 + s]     = (_Float16)dot16(p2h[u], a0, b0, c0);
            krow[(o+1)*56 + s] = (_Float16)dot16(p2h[u], a1, b1, c1);
          }
        }
        { // V
          uint4 a0 = g1a[r0+1568], b0 = g1b[r0+1568], a1 = g1a[r0+1617], b1 = g1b[r0+1617];
          float c0 = gcq[r0+1568], c1 = gcq[r0+1617];
          #pragma unroll
          for (int u = 0; u < 2; ++u)
            v1h[u][op] = packh2(dot16(p2h[u], a0, b0, c0), dot16(p2h[u], a1, b1, c1));
        }
      }
    }
    __syncthreads();

    // ---- P3: S1[d,e] via dot2 over s-pairs; lane=(d2,e2) 8x8, loop samples ----
    {
      const u32 d2 = lane >> 3, e2 = lane & 7u;
      #pragma unroll
      for (int u = 0; u < 2; ++u) {
        char* su = pw + u*4096;
        const u32* qw = (const u32*)su;
        const u32* kw = (const u32*)(su + 1792);
        const u32* qA = qw + (2u*d2) * 28u;
        const u32* qB = qA + 28u;
        const u32* kA = kw + (2u*e2) * 28u;
        const u32* kB = kA + 28u;
        float a00 = 0.f, a01 = 0.f, a10 = 0.f, a11 = 0.f;
        #pragma unroll
        for (int t7 = 0; t7 < 6; ++t7) {
          uint4 qa = *(const uint4*)(qA + 4*t7);
          uint4 qb = *(const uint4*)(qB + 4*t7);
          uint4 ka = *(const uint4*)(kA + 4*t7);
          uint4 kb = *(const uint4*)(kB + 4*t7);
          a00 = dot2u(qa.x, ka.x, a00); a00 = dot2u(qa.y, ka.y, a00);
          a00 = dot2u(qa.z, ka.z, a00); a00 = dot2u(qa.w, ka.w, a00);
          a01 = dot2u(qa.x, kb.x, a01); a01 = dot2u(qa.y, kb.y, a01);
          a01 = dot2u(qa.z, kb.z, a01); a01 = dot2u(qa.w, kb.w, a01);
          a10 = dot2u(qb.x, ka.x, a10); a10 = dot2u(qb.y, ka.y, a10);
          a10 = dot2u(qb.z, ka.z, a10); a10 = dot2u(qb.w, ka.w, a10);
          a11 = dot2u(qb.x, kb.x, a11); a11 = dot2u(qb.y, kb.y, a11);
          a11 = dot2u(qb.z, kb.z, a11); a11 = dot2u(qb.w, kb.w, a11);
        }
        {
          float q0t = (float)((const _Float16*)qA)[48];
          float q1t = (float)((const _Float16*)qB)[48];
          float k0t = (float)((const _Float16*)kA)[48];
          float k1t = (float)((const _Float16*)kB)[48];
          a00 = fmaf(q0t, k0t, a00); a01 = fmaf(q0t, k1t, a01);
          a10 = fmaf(q1t, k0t, a10); a11 = fmaf(q1t, k1t, a11);
        }
        u32* s1 = (u32*)(su + 3584);
        s1[(2u*d2)*8u + e2]   = packh2(a00, a01);
        s1[(2u*d2+1)*8u + e2] = packh2(a10, a11);
      }
    }
    __syncthreads();

    // ---- P4a: out1 + softmax16 -> th4 ----
    if (s < 49u) {
      #pragma unroll
      for (int u = 0; u < 2; ++u) {
        char* su = pw + u*4096;
        const u32* s1 = (const u32*)(su + 3584);
        float od[16];
        #pragma unroll
        for (int d = 0; d < 16; ++d) {
          uint4 sa = *(const uint4*)&s1[d*8];
          uint4 sb = *(const uint4*)&s1[d*8 + 4];
          float acc = dot2u(sa.x, v1h[u][0], 0.f);
          acc = dot2u(sa.y, v1h[u][1], acc);
          acc = dot2u(sa.z, v1h[u][2], acc);
          acc = dot2u(sa.w, v1h[u][3], acc);
          acc = dot2u(sb.x, v1h[u][4], acc);
          acc = dot2u(sb.y, v1h[u][5], acc);
          acc = dot2u(sb.z, v1h[u][6], acc);
          acc = dot2u(sb.w, v1h[u][7], acc);
          od[d] = acc;
        }
        float m = od[0];
        #pragma unroll
        for (int d = 1; d < 16; ++d) m = fmaxf(m, od[d]);
        float sum = 0.f;
        #pragma unroll
        for (int d = 0; d < 16; ++d) { od[d] = __expf(od[d] - m); sum += od[d]; }
        float rs = 1.0f / sum;
        #pragma unroll
        for (int j = 0; j < 8; ++j) th4[u][j] = packh2(od[2*j]*rs, od[2*j+1]*rs);
      }
    }

    // ---- P4b: proj2 from global weights ----
    if (s < 49u) {
      #pragma unroll
      for (int op = 0; op < 4; ++op) {
        const int o = 2*op;
        const int r0 = o*49 + (int)s;
        { // Q
          uint4 a0 = g2a[r0], b0 = g2b[r0], a1 = g2a[r0+49], b1 = g2b[r0+49];
          #pragma unroll
          for (int u = 0; u < 2; ++u) {
            _Float16* qrow = (_Float16*)(pw + u*4096);
            qrow[o*56 + s]     = (_Float16)dot16(th4[u], a0, b0, 0.f);
            qrow[(o+1)*56 + s] = (_Float16)dot16(th4[u], a1, b1, 0.f);
          }
        }
        { // K
          uint4 a0 = g2a[r0+392], b0 = g2b[r0+392], a1 = g2a[r0+441], b1 = g2b[r0+441];
          #pragma unroll
          for (int u = 0; u < 2; ++u) {
            _Float16* krow = (_Float16*)(pw + u*4096 + 896);
            krow[o*56 + s]     = (_Float16)dot16(th4[u], a0, b0, 0.f);
            krow[(o+1)*56 + s] = (_Float16)dot16(th4[u], a1, b1, 0.f);
          }
        }
        { // V
          uint4 a0 = g2a[r0+784], b0 = g2b[r0+784], a1 = g2a[r0+833], b1 = g2b[r0+833];
          #pragma unroll
          for (int u = 0; u < 2; ++u)
            v2h[u][op] = packh2(dot16(th4[u], a0, b0, 0.f), dot16(th4[u], a1, b1, 0.f));
        }
      }
    }
    __syncthreads();

    // ---- P5: S2[d,e] 8x8; lane=(u, d, e2): 32 lanes per sample ----
    {
      const u32 uu = lane >> 5, d = (lane >> 2) & 7u, e2 = lane & 3u;
      char* su = pw + uu*4096;
      const u32* qw = (const u32*)su;
      const u32* kw = (const u32*)(su + 896);
      const u32* qA = qw + d * 28u;
      const u32* kA = kw + (2u*e2) * 28u;
      const u32* kB = kA + 28u;
      float a0 = 0.f, a1 = 0.f;
      #pragma unroll
      for (int t7 = 0; t7 < 6; ++t7) {
        uint4 qa = *(const uint4*)(qA + 4*t7);
        uint4 ka = *(const uint4*)(kA + 4*t7);
        uint4 kb = *(const uint4*)(kB + 4*t7);
        a0 = dot2u(qa.x, ka.x, a0); a0 = dot2u(qa.y, ka.y, a0);
        a0 = dot2u(qa.z, ka.z, a0); a0 = dot2u(qa.w, ka.w, a0);
        a1 = dot2u(qa.x, kb.x, a1); a1 = dot2u(qa.y, kb.y, a1);
        a1 = dot2u(qa.z, kb.z, a1); a1 = dot2u(qa.w, kb.w, a1);
      }
      {
        float qt = (float)((const _Float16*)qA)[48];
        float k0t = (float)((const _Float16*)kA)[48];
        float k1t = (float)((const _Float16*)kB)[48];
        a0 = fmaf(qt, k0t, a0); a1 = fmaf(qt, k1t, a1);
      }
      u32* s2 = (u32*)(su + 3584);
      s2[d*4u + e2] = packh2(a0, a1);
    }
    __syncthreads();

    // ---- P6: out2 + softmax8 -> t3h ----
    if (s < 49u) {
      #pragma unroll
      for (int u = 0; u < 2; ++u) {
        char* su = pw + u*4096;
        const u32* s2 = (const u32*)(su + 3584);
        float od[8];
        #pragma unroll
        for (int d = 0; d < 8; ++d) {
          uint4 sr = *(const uint4*)&s2[d*4];
          float acc = dot2u(sr.x, v2h[u][0], 0.f);
          acc = dot2u(sr.y, v2h[u][1], acc);
          acc = dot2u(sr.z, v2h[u][2], acc);
          acc = dot2u(sr.w, v2h[u][3], acc);
          od[d] = acc;
        }
        float m = od[0];
        #pragma unroll
        for (int d = 1; d < 8; ++d) m = fmaxf(m, od[d]);
        float sum = 0.f;
        #pragma unroll
        for (int d = 0; d < 8; ++d) { od[d] = __expf(od[d] - m); sum += od[d]; }
        float rs = 1.0f / sum;
        uint4 tw;
        tw.x = packh2(od[0]*rs, od[1]*rs);
        tw.y = packh2(od[2]*rs, od[3]*rs);
        tw.z = packh2(od[4]*rs, od[5]*rs);
        tw.w = packh2(od[6]*rs, od[7]*rs);
        *(uint4*)((u32*)su + s*4u) = tw;    // t3h overwrites dead Q2 region
      }
    }
    __syncthreads();

    // ---- P7: fc1 halves; lane=(u, h, half) ----
    {
      const u32 uu = lane >> 5, h = (lane >> 1) & 15u, half = lane & 1u;
      char* su = pw + uu*4096;
      const u32* t3 = (const u32*)su;
      float acc = half ? 0.f : f1bg[h];
      #pragma unroll
      for (int jj = 0; jj < 25; ++jj) {
        int j = (int)(half * 25u) + jj;
        if (j < 49) {
          uint4 tj = *(const uint4*)&t3[j*4];
          uint4 wj = f1hg[h*49u + (u32)j];
          acc = dot2u(tj.x, wj.x, acc);
          acc = dot2u(tj.y, wj.y, acc);
          acc = dot2u(tj.z, wj.z, acc);
          acc = dot2u(tj.w, wj.w, acc);
        }
      }
      float* prt = (float*)(su + 3584 + 192);
      prt[h*2u + half] = acc;
    }
    __syncthreads();

    // ---- fc2 (merge + relu + dot); lane=(u, c<10) ----
    {
      const u32 uu = lane >> 5, c = lane & 31u;
      char* su = pw + uu*4096;
      if (c < 10u) {
        const float4* pv4 = (const float4*)(su + 3584 + 192);
        float hb[16];
        #pragma unroll
        for (int g = 0; g < 8; ++g) {
          float4 pv = pv4[g];
          hb[2*g]   = fmaxf(pv.x + pv.y, 0.f);
          hb[2*g+1] = fmaxf(pv.z + pv.w, 0.f);
        }
        const float* wr = f2wg + c*16u;
        float acc = f2bg[c];
        #pragma unroll
        for (int h = 0; h < 16; ++h) acc = fmaf(hb[h], wr[h], acc);
        float* lg = (float*)(su + 3584 + 384);
        lg[c] = acc;
      }
    }
    __syncthreads();

    // ---- softmax10 + store ----
    {
      const u32 uu = lane >> 5, c = lane & 31u;
      char* su = pw + uu*4096;
      if (c < 10u) {
        const float* lg = (const float*)(su + 3584 + 384);
        float mx = lg[0];
        #pragma unroll
        for (int i = 1; i < 10; ++i) mx = fmaxf(mx, lg[i]);
        float sum = 0.f;
        #pragma unroll
        for (int i = 0; i < 10; ++i) sum += __expf(lg[i] - mx);
        out[(size_t)(bbase + uu) * 10u + c] = __expf(lg[c] - mx) / sum;
      }
    }
    __syncthreads();   // protect per-wave LDS reuse next iteration
  }
}

extern "C" void kernel_launch(void* const* d_in, const int* in_sizes, int n_in,
                              void* d_out, int out_size, void* d_ws, size_t ws_size,
                              hipStream_t stream)
{
  const float* x   = (const float*)d_in[0];
  const float* pe  = (const float*)d_in[1];
  const float* wq1 = (const float*)d_in[2];
  const float* wk1 = (const float*)d_in[3];
  const float* wv1 = (const float*)d_in[4];
  const float* wq2 = (const float*)d_in[5];
  const float* wk2 = (const float*)d_in[6];
  const float* wv2 = (const float*)d_in[7];
  const float* f1w = (const float*)d_in[8];
  const float* f1b = (const float*)d_in[9];
  const float* f2w = (const float*)d_in[10];
  const float* f2b = (const float*)d_in[11];
  char* ws = (char*)d_ws;
  float* out = (float*)d_out;

  hipLaunchKernelGGL(vit_prep, dim3(27), dim3(256), 0, stream,
                     pe, wq1, wk1, wv1, wq2, wk2, wv2, f1w, f1b, f2w, f2b, ws);
  hipLaunchKernelGGL(vit_main, dim3(256), dim3(256), 0, stream, x, ws, out);
}

// Round 5
// 292.089 us; speedup vs baseline: 2.4764x; 2.4764x over previous
//
#include <hip/hip_runtime.h>
#include <cstdint>

typedef unsigned int u32;
typedef unsigned short u16;
typedef _Float16 h2 __attribute__((ext_vector_type(2)));

// ---------------- workspace byte offsets (written by vit_prep) ----------------
#define WS_W1A   0        // [3*16*49][8] f16 : W1 i<8   (Q rows pre-scaled 1/7)
#define WS_W1B   37632    // [3*16*49][8] f16 : W1 i 8..16
#define WS_CQ    75264    // f32[2352]  pos-emb-folded bias (Q part pre-scaled)
#define WS_W2A   84672    // [3*8*49][8] f16 : W2 i<8 (Q rows pre-scaled 1/7)
#define WS_W2B   103488   // [3*8*49][8] f16 : W2 i 8..16
#define WS_F1H   122304   // u32[16*196] fc1 weights as f16 pairs (bias NOT folded)
#define WS_F1B   134848   // f32[16]
#define WS_F2W   134912   // f32[160]
#define WS_F2B   135552   // f32[10]

__device__ __forceinline__ u32 packh2(float a, float b) {
  h2 h; h.x = (_Float16)a; h.y = (_Float16)b;
  return __builtin_bit_cast(u32, h);
}
__device__ __forceinline__ float dot2u(u32 a, u32 b, float c) {
#if __has_builtin(__builtin_amdgcn_fdot2)
  return __builtin_amdgcn_fdot2(__builtin_bit_cast(h2, a), __builtin_bit_cast(h2, b), c, false);
#else
  h2 ha = __builtin_bit_cast(h2, a), hb = __builtin_bit_cast(h2, b);
  return c + (float)ha.x * (float)hb.x + (float)ha.y * (float)hb.y;
#endif
}
__device__ __forceinline__ float dot16(const u32* t, uint4 a, uint4 b, float c) {
  c = dot2u(t[0], a.x, c); c = dot2u(t[1], a.y, c);
  c = dot2u(t[2], a.z, c); c = dot2u(t[3], a.w, c);
  c = dot2u(t[4], b.x, c); c = dot2u(t[5], b.y, c);
  c = dot2u(t[6], b.z, c); c = dot2u(t[7], b.w, c);
  return c;
}

// ---------------- prep (unchanged) ----------------
extern "C" __global__ void vit_prep(
    const float* __restrict__ pe,
    const float* __restrict__ wq1, const float* __restrict__ wk1, const float* __restrict__ wv1,
    const float* __restrict__ wq2, const float* __restrict__ wk2, const float* __restrict__ wv2,
    const float* __restrict__ fw1, const float* __restrict__ fb1,
    const float* __restrict__ fw2, const float* __restrict__ fb2,
    char* __restrict__ ws)
{
  const int t = blockIdx.x * 256 + threadIdx.x;
  _Float16* w1aH = (_Float16*)(ws + WS_W1A);
  _Float16* w1bH = (_Float16*)(ws + WS_W1B);
  float*    cq   = (float*)(ws + WS_CQ);
  _Float16* w2aH = (_Float16*)(ws + WS_W2A);
  _Float16* w2bH = (_Float16*)(ws + WS_W2B);
  u32* f1h = (u32*)(ws + WS_F1H);
  float* o1b = (float*)(ws + WS_F1B);
  float* o2w = (float*)(ws + WS_F2W);
  float* o2b = (float*)(ws + WS_F2B);

  if (t < 2352) {                       // W1 rows: t = (p*16+o)*49+s
    int p = t / 784, rem = t % 784;
    int o = rem / 49, s = rem % 49;
    const float* W = (p == 0 ? wq1 : (p == 1 ? wk1 : wv1)) + s*512 + o*32;
    float sc = (p == 0) ? (1.0f/7.0f) : 1.0f;   // fold attn scale into Q
    #pragma unroll
    for (int i = 0; i < 8; ++i) w1aH[t*8 + i] = (_Float16)(W[i] * sc);
    #pragma unroll
    for (int i = 0; i < 8; ++i) w1bH[t*8 + i] = (_Float16)(W[8 + i] * sc);
    float acc = 0.f;
    #pragma unroll
    for (int i = 0; i < 16; ++i) acc += pe[s*16 + i] * W[16 + i];
    cq[t] = acc * sc;
  } else if (t < 3528) {                // W2 rows: u = (p*8+o)*49+s
    int u = t - 2352;
    int p = u / 392, rem = u % 392;
    int o = rem / 49, s = rem % 49;
    const float* W = (p == 0 ? wq2 : (p == 1 ? wk2 : wv2)) + s*128 + o*16;
    float sc = (p == 0) ? (1.0f/7.0f) : 1.0f;
    #pragma unroll
    for (int i = 0; i < 8; ++i) w2aH[u*8 + i] = (_Float16)(W[i] * sc);
    #pragma unroll
    for (int i = 0; i < 8; ++i) w2bH[u*8 + i] = (_Float16)(W[8 + i] * sc);
  } else if (t < 6664) {                // fc1 f16 pairs: u = h*196 + jc
    int u = t - 3528;
    int h = u / 196, jc = u % 196;
    f1h[u] = packh2(fw1[h*392 + 2*jc], fw1[h*392 + 2*jc + 1]);
  } else if (t < 6680) {
    int u = t - 6664; o1b[u] = fb1[u];
  } else if (t < 6840) {
    int u = t - 6680; o2w[u] = fw2[u];
  } else if (t < 6850) {
    int u = t - 6840; o2b[u] = fb2[u];
  }
}

// ---------------- main fused kernel ----------------
// block=256 (4 waves), grid=2048, NS=2 samples/wave, 8 samples/block, no iter loop.
// ALL weights from global (L2-resident ~135 KB). LDS = per-wave scratch only:
//   per sample region 4096 B:
//     su+0    : Q1 f16 [16][56] (1792)  -> later Q2 [8][56] (896) / K2 @+896 / t3h u32[49][4] (784)
//     su+1792 : K1 f16 [16][56] (1792)
//     su+3584 : S1 u32[16][8] (512) -> S2 u32[8][4] @+0; prt f32[16][2] @+192; lg f32[10] @+384
// block LDS = 4 waves * 2 * 4096 = 32768 B.
// __launch_bounds__(256,2): VGPR cap 256 — R4's (256,4) forced 64 VGPR -> spills.
extern "C" __global__ void __launch_bounds__(256, 2)
vit_main(const float* __restrict__ x, const char* __restrict__ ws, float* __restrict__ out)
{
  __shared__ uint4 smem4[32768 / 16];
  char* smem = (char*)smem4;
  const u32 tid  = threadIdx.x;
  const u32 lane = tid & 63u;
  const u32 wv   = tid >> 6;

  const uint4* g1a = (const uint4*)(ws + WS_W1A);
  const uint4* g1b = (const uint4*)(ws + WS_W1B);
  const float* gcq = (const float*)(ws + WS_CQ);
  const uint4* g2a = (const uint4*)(ws + WS_W2A);
  const uint4* g2b = (const uint4*)(ws + WS_W2B);
  const uint4* f1hg = (const uint4*)(ws + WS_F1H);
  const float* f1bg = (const float*)(ws + WS_F1B);
  const float* f2wg = (const float*)(ws + WS_F2W);
  const float* f2bg = (const float*)(ws + WS_F2B);

  char* pw = smem + wv * 8192;
  const u32 s = lane;
  const u32 pr = s / 7u, pc = s - pr * 7u;

  const u32 bbase = blockIdx.x * 8u + wv * 2u;

  u32 p2h[2][8];   // patch h2 pairs
  u32 v1h[2][8];   // V1 e-pairs
  u32 th4[2][8];   // tok2 pairs
  u32 v2h[2][4];   // V2 e-pairs

  // ---- P1: patchify to registers ----
  if (s < 49u) {
    #pragma unroll
    for (int u = 0; u < 2; ++u) {
      const float* xb = x + (size_t)(bbase + u) * 2352u;
      #pragma unroll
      for (int r = 0; r < 4; ++r) {
        const float* rp = xb + (4u*pr + r) * 28u + 4u*pc;
        float4 rr = *(const float4*)rp;
        float4 gg = *(const float4*)(rp + 784);
        float4 bb = *(const float4*)(rp + 1568);
        float g0 = 0.299f*rr.x + 0.587f*gg.x + 0.114f*bb.x;
        float g1 = 0.299f*rr.y + 0.587f*gg.y + 0.114f*bb.y;
        float g2 = 0.299f*rr.z + 0.587f*gg.z + 0.114f*bb.z;
        float g3 = 0.299f*rr.w + 0.587f*gg.w + 0.114f*bb.w;
        p2h[u][r*2]   = packh2(g0, g1);
        p2h[u][r*2+1] = packh2(g2, g3);
      }
    }
  }

  // ---- P2: proj1 from global weights (QKV-split to bound reg pressure) ----
  if (s < 49u) {
    #pragma unroll
    for (int op = 0; op < 8; ++op) {
      const int o = 2*op;
      const int r0 = o*49 + (int)s;
      { // Q
        uint4 a0 = g1a[r0], b0 = g1b[r0], a1 = g1a[r0+49], b1 = g1b[r0+49];
        float c0 = gcq[r0], c1 = gcq[r0+49];
        #pragma unroll
        for (int u = 0; u < 2; ++u) {
          _Float16* qrow = (_Float16*)(pw + u*4096);
          qrow[o*56 + s]     = (_Float16)dot16(p2h[u], a0, b0, c0);
          qrow[(o+1)*56 + s] = (_Float16)dot16(p2h[u], a1, b1, c1);
        }
      }
      { // K
        uint4 a0 = g1a[r0+784], b0 = g1b[r0+784], a1 = g1a[r0+833], b1 = g1b[r0+833];
        float c0 = gcq[r0+784], c1 = gcq[r0+833];
        #pragma unroll
        for (int u = 0; u < 2; ++u) {
          _Float16* krow = (_Float16*)(pw + u*4096 + 1792);
          krow[o*56 + s]     = (_Float16)dot16(p2h[u], a0, b0, c0);
          krow[(o+1)*56 + s] = (_Float16)dot16(p2h[u], a1, b1, c1);
        }
      }
      { // V
        uint4 a0 = g1a[r0+1568], b0 = g1b[r0+1568], a1 = g1a[r0+1617], b1 = g1b[r0+1617];
        float c0 = gcq[r0+1568], c1 = gcq[r0+1617];
        #pragma unroll
        for (int u = 0; u < 2; ++u)
          v1h[u][op] = packh2(dot16(p2h[u], a0, b0, c0), dot16(p2h[u], a1, b1, c1));
      }
    }
  }
  __syncthreads();

  // ---- P3: S1[d,e] via dot2 over s-pairs; lane=(d2,e2) 8x8, loop samples ----
  {
    const u32 d2 = lane >> 3, e2 = lane & 7u;
    #pragma unroll
    for (int u = 0; u < 2; ++u) {
      char* su = pw + u*4096;
      const u32* qw = (const u32*)su;
      const u32* kw = (const u32*)(su + 1792);
      const u32* qA = qw + (2u*d2) * 28u;
      const u32* qB = qA + 28u;
      const u32* kA = kw + (2u*e2) * 28u;
      const u32* kB = kA + 28u;
      float a00 = 0.f, a01 = 0.f, a10 = 0.f, a11 = 0.f;
      #pragma unroll
      for (int t7 = 0; t7 < 6; ++t7) {
        uint4 qa = *(const uint4*)(qA + 4*t7);
        uint4 qb = *(const uint4*)(qB + 4*t7);
        uint4 ka = *(const uint4*)(kA + 4*t7);
        uint4 kb = *(const uint4*)(kB + 4*t7);
        a00 = dot2u(qa.x, ka.x, a00); a00 = dot2u(qa.y, ka.y, a00);
        a00 = dot2u(qa.z, ka.z, a00); a00 = dot2u(qa.w, ka.w, a00);
        a01 = dot2u(qa.x, kb.x, a01); a01 = dot2u(qa.y, kb.y, a01);
        a01 = dot2u(qa.z, kb.z, a01); a01 = dot2u(qa.w, kb.w, a01);
        a10 = dot2u(qb.x, ka.x, a10); a10 = dot2u(qb.y, ka.y, a10);
        a10 = dot2u(qb.z, ka.z, a10); a10 = dot2u(qb.w, ka.w, a10);
        a11 = dot2u(qb.x, kb.x, a11); a11 = dot2u(qb.y, kb.y, a11);
        a11 = dot2u(qb.z, kb.z, a11); a11 = dot2u(qb.w, kb.w, a11);
      }
      {
        float q0t = (float)((const _Float16*)qA)[48];
        float q1t = (float)((const _Float16*)qB)[48];
        float k0t = (float)((const _Float16*)kA)[48];
        float k1t = (float)((const _Float16*)kB)[48];
        a00 = fmaf(q0t, k0t, a00); a01 = fmaf(q0t, k1t, a01);
        a10 = fmaf(q1t, k0t, a10); a11 = fmaf(q1t, k1t, a11);
      }
      u32* s1 = (u32*)(su + 3584);
      s1[(2u*d2)*8u + e2]   = packh2(a00, a01);
      s1[(2u*d2+1)*8u + e2] = packh2(a10, a11);
    }
  }
  __syncthreads();

  // ---- P4a: out1 + softmax16 -> th4 ----
  if (s < 49u) {
    #pragma unroll
    for (int u = 0; u < 2; ++u) {
      char* su = pw + u*4096;
      const u32* s1 = (const u32*)(su + 3584);
      float od[16];
      #pragma unroll
      for (int d = 0; d < 16; ++d) {
        uint4 sa = *(const uint4*)&s1[d*8];
        uint4 sb = *(const uint4*)&s1[d*8 + 4];
        float acc = dot2u(sa.x, v1h[u][0], 0.f);
        acc = dot2u(sa.y, v1h[u][1], acc);
        acc = dot2u(sa.z, v1h[u][2], acc);
        acc = dot2u(sa.w, v1h[u][3], acc);
        acc = dot2u(sb.x, v1h[u][4], acc);
        acc = dot2u(sb.y, v1h[u][5], acc);
        acc = dot2u(sb.z, v1h[u][6], acc);
        acc = dot2u(sb.w, v1h[u][7], acc);
        od[d] = acc;
      }
      float m = od[0];
      #pragma unroll
      for (int d = 1; d < 16; ++d) m = fmaxf(m, od[d]);
      float sum = 0.f;
      #pragma unroll
      for (int d = 0; d < 16; ++d) { od[d] = __expf(od[d] - m); sum += od[d]; }
      float rs = 1.0f / sum;
      #pragma unroll
      for (int j = 0; j < 8; ++j) th4[u][j] = packh2(od[2*j]*rs, od[2*j+1]*rs);
    }
  }

  // ---- P4b: proj2 from global weights ----
  if (s < 49u) {
    #pragma unroll
    for (int op = 0; op < 4; ++op) {
      const int o = 2*op;
      const int r0 = o*49 + (int)s;
      { // Q
        uint4 a0 = g2a[r0], b0 = g2b[r0], a1 = g2a[r0+49], b1 = g2b[r0+49];
        #pragma unroll
        for (int u = 0; u < 2; ++u) {
          _Float16* qrow = (_Float16*)(pw + u*4096);
          qrow[o*56 + s]     = (_Float16)dot16(th4[u], a0, b0, 0.f);
          qrow[(o+1)*56 + s] = (_Float16)dot16(th4[u], a1, b1, 0.f);
        }
      }
      { // K
        uint4 a0 = g2a[r0+392], b0 = g2b[r0+392], a1 = g2a[r0+441], b1 = g2b[r0+441];
        #pragma unroll
        for (int u = 0; u < 2; ++u) {
          _Float16* krow = (_Float16*)(pw + u*4096 + 896);
          krow[o*56 + s]     = (_Float16)dot16(th4[u], a0, b0, 0.f);
          krow[(o+1)*56 + s] = (_Float16)dot16(th4[u], a1, b1, 0.f);
        }
      }
      { // V
        uint4 a0 = g2a[r0+784], b0 = g2b[r0+784], a1 = g2a[r0+833], b1 = g2b[r0+833];
        #pragma unroll
        for (int u = 0; u < 2; ++u)
          v2h[u][op] = packh2(dot16(th4[u], a0, b0, 0.f), dot16(th4[u], a1, b1, 0.f));
      }
    }
  }
  __syncthreads();

  // ---- P5: S2[d,e] 8x8; lane=(u, d, e2): 32 lanes per sample ----
  {
    const u32 uu = lane >> 5, d = (lane >> 2) & 7u, e2 = lane & 3u;
    char* su = pw + uu*4096;
    const u32* qw = (const u32*)su;
    const u32* kw = (const u32*)(su + 896);
    const u32* qA = qw + d * 28u;
    const u32* kA = kw + (2u*e2) * 28u;
    const u32* kB = kA + 28u;
    float a0 = 0.f, a1 = 0.f;
    #pragma unroll
    for (int t7 = 0; t7 < 6; ++t7) {
      uint4 qa = *(const uint4*)(qA + 4*t7);
      uint4 ka = *(const uint4*)(kA + 4*t7);
      uint4 kb = *(const uint4*)(kB + 4*t7);
      a0 = dot2u(qa.x, ka.x, a0); a0 = dot2u(qa.y, ka.y, a0);
      a0 = dot2u(qa.z, ka.z, a0); a0 = dot2u(qa.w, ka.w, a0);
      a1 = dot2u(qa.x, kb.x, a1); a1 = dot2u(qa.y, kb.y, a1);
      a1 = dot2u(qa.z, kb.z, a1); a1 = dot2u(qa.w, kb.w, a1);
    }
    {
      float qt = (float)((const _Float16*)qA)[48];
      float k0t = (float)((const _Float16*)kA)[48];
      float k1t = (float)((const _Float16*)kB)[48];
      a0 = fmaf(qt, k0t, a0); a1 = fmaf(qt, k1t, a1);
    }
    u32* s2 = (u32*)(su + 3584);
    s2[d*4u + e2] = packh2(a0, a1);
  }
  __syncthreads();

  // ---- P6: out2 + softmax8 -> t3h ----
  if (s < 49u) {
    #pragma unroll
    for (int u = 0; u < 2; ++u) {
      char* su = pw + u*4096;
      const u32* s2 = (const u32*)(su + 3584);
      float od[8];
      #pragma unroll
      for (int d = 0; d < 8; ++d) {
        uint4 sr = *(const uint4*)&s2[d*4];
        float acc = dot2u(sr.x, v2h[u][0], 0.f);
        acc = dot2u(sr.y, v2h[u][1], acc);
        acc = dot2u(sr.z, v2h[u][2], acc);
        acc = dot2u(sr.w, v2h[u][3], acc);
        od[d] = acc;
      }
      float m = od[0];
      #pragma unroll
      for (int d = 1; d < 8; ++d) m = fmaxf(m, od[d]);
      float sum = 0.f;
      #pragma unroll
      for (int d = 0; d < 8; ++d) { od[d] = __expf(od[d] - m); sum += od[d]; }
      float rs = 1.0f / sum;
      uint4 tw;
      tw.x = packh2(od[0]*rs, od[1]*rs);
      tw.y = packh2(od[2]*rs, od[3]*rs);
      tw.z = packh2(od[4]*rs, od[5]*rs);
      tw.w = packh2(od[6]*rs, od[7]*rs);
      *(uint4*)((u32*)su + s*4u) = tw;    // t3h overwrites dead Q2 region
    }
  }
  __syncthreads();

  // ---- P7: fc1 halves; lane=(u, h, half) ----
  {
    const u32 uu = lane >> 5, h = (lane >> 1) & 15u, half = lane & 1u;
    char* su = pw + uu*4096;
    const u32* t3 = (const u32*)su;
    float acc = half ? 0.f : f1bg[h];
    #pragma unroll
    for (int jj = 0; jj < 25; ++jj) {
      int j = (int)(half * 25u) + jj;
      if (j < 49) {
        uint4 tj = *(const uint4*)&t3[j*4];
        uint4 wj = f1hg[h*49u + (u32)j];
        acc = dot2u(tj.x, wj.x, acc);
        acc = dot2u(tj.y, wj.y, acc);
        acc = dot2u(tj.z, wj.z, acc);
        acc = dot2u(tj.w, wj.w, acc);
      }
    }
    float* prt = (float*)(su + 3584 + 192);
    prt[h*2u + half] = acc;
  }
  __syncthreads();

  // ---- fc2 (merge + relu + dot); lane=(u, c<10) ----
  {
    const u32 uu = lane >> 5, c = lane & 31u;
    char* su = pw + uu*4096;
    if (c < 10u) {
      const float4* pv4 = (const float4*)(su + 3584 + 192);
      float hb[16];
      #pragma unroll
      for (int g = 0; g < 8; ++g) {
        float4 pv = pv4[g];
        hb[2*g]   = fmaxf(pv.x + pv.y, 0.f);
        hb[2*g+1] = fmaxf(pv.z + pv.w, 0.f);
      }
      const float* wr = f2wg + c*16u;
      float acc = f2bg[c];
      #pragma unroll
      for (int h = 0; h < 16; ++h) acc = fmaf(hb[h], wr[h], acc);
      float* lg = (float*)(su + 3584 + 384);
      lg[c] = acc;
    }
  }
  __syncthreads();

  // ---- softmax10 + store ----
  {
    const u32 uu = lane >> 5, c = lane & 31u;
    char* su = pw + uu*4096;
    if (c < 10u) {
      const float* lg = (const float*)(su + 3584 + 384);
      float mx = lg[0];
      #pragma unroll
      for (int i = 1; i < 10; ++i) mx = fmaxf(mx, lg[i]);
      float sum = 0.f;
      #pragma unroll
      for (int i = 0; i < 10; ++i) sum += __expf(lg[i] - mx);
      out[(size_t)(bbase + uu) * 10u + c] = __expf(lg[c] - mx) / sum;
    }
  }
}

extern "C" void kernel_launch(void* const* d_in, const int* in_sizes, int n_in,
                              void* d_out, int out_size, void* d_ws, size_t ws_size,
                              hipStream_t stream)
{
  const float* x   = (const float*)d_in[0];
  const float* pe  = (const float*)d_in[1];
  const float* wq1 = (const float*)d_in[2];
  const float* wk1 = (const float*)d_in[3];
  const float* wv1 = (const float*)d_in[4];
  const float* wq2 = (const float*)d_in[5];
  const float* wk2 = (const float*)d_in[6];
  const float* wv2 = (const float*)d_in[7];
  const float* f1w = (const float*)d_in[8];
  const float* f1b = (const float*)d_in[9];
  const float* f2w = (const float*)d_in[10];
  const float* f2b = (const float*)d_in[11];
  char* ws = (char*)d_ws;
  float* out = (float*)d_out;

  hipLaunchKernelGGL(vit_prep, dim3(27), dim3(256), 0, stream,
                     pe, wq1, wk1, wv1, wq2, wk2, wv2, f1w, f1b, f2w, f2b, ws);
  hipLaunchKernelGGL(vit_main, dim3(2048), dim3(256), 0, stream, x, ws, out);
}